// Round 4
// baseline (237.355 us; speedup 1.0000x reference)
//
#include <hip/hip_runtime.h>

#define B_SZ 8
#define C_IN 64
#define N_PT 4096
#define BN_TOT 32768          // B*N
#define KNB 20                // neighbors
#define KSZ 20                // kernel_size
#define C_OUT 64
#define BN_EPS 1e-5f

// ---------------------------------------------------------------------------
// K0: build shuffled+transposed conv weight w2t[c][o] = conv_w[o][smap(c)]
//     smap(c) = (c%16)*4 + c/16  ->  placed via inverse map from coalesced read.
//     Also zero BN sums + last-block counter. 16 blocks x 256 threads.
// ---------------------------------------------------------------------------
__global__ void k0_prep(const float* __restrict__ conv_w,
                        float* __restrict__ w2t,
                        float* __restrict__ sums /* 128 + ctr */) {
    int i = blockIdx.x * 256 + threadIdx.x;      // 0..4095
    float v = conv_w[i];                         // coalesced
    int o = i >> 6, co = i & 63;
    int cn = ((co & 3) << 4) | (co >> 2);        // smap^{-1}
    w2t[cn * 64 + o] = v;
    if (blockIdx.x == 0 && threadIdx.x < 132) sums[threadIdx.x] = 0.f;
}

// ---------------------------------------------------------------------------
// K1: G[m][o] = sum_c w2t[c][o] * feature[b][c][n],  m = b*N + n
//     512 blocks x 512 threads (8 waves). Wave w: o in [w*8, w*8+8), lane=point.
// ---------------------------------------------------------------------------
__global__ __launch_bounds__(512) void k1_gemm(const float* __restrict__ feat,
                                               const float* __restrict__ w2t,
                                               float* __restrict__ G) {
    __shared__ float fl[C_IN * 64];              // [c][p], 16 KiB
    const int b  = blockIdx.x >> 6;
    const int n0 = (blockIdx.x & 63) << 6;
    const int t  = threadIdx.x;

    const float4* fsrc = reinterpret_cast<const float4*>(
        feat + (size_t)b * C_IN * N_PT + n0);
    float4* fl4 = reinterpret_cast<float4*>(fl);
#pragma unroll
    for (int j = 0; j < 2; ++j) {
        int idx = j * 512 + t;                   // 0..1023 float4 slots
        int c = idx >> 4, p4 = idx & 15;
        fl4[idx] = fsrc[c * (N_PT / 4) + p4];
    }
    __syncthreads();

    const int lane = t & 63;
    const int ob = __builtin_amdgcn_readfirstlane((t >> 6) << 3); // 0,8,..,56

    float acc[8];
#pragma unroll
    for (int j = 0; j < 8; ++j) acc[j] = 0.f;

#pragma unroll 8
    for (int c = 0; c < C_IN; ++c) {
        float fc = fl[c * 64 + lane];            // stride-1, conflict-free
        const float* wrow = w2t + c * 64 + ob;   // wave-uniform -> s_load
#pragma unroll
        for (int j = 0; j < 8; ++j) acc[j] += fc * wrow[j];
    }

    size_t m = (size_t)b * N_PT + n0 + lane;
    float4* gdst = reinterpret_cast<float4*>(G + m * 64 + ob);
    gdst[0] = make_float4(acc[0], acc[1], acc[2], acc[3]);
    gdst[1] = make_float4(acc[4], acc[5], acc[6], acc[7]);
}

// ---------------------------------------------------------------------------
// K2: per point n: out[o,s] = sum_k G[idx[n,k]][o] * P[n][k][s]
//     omax[n][o] = max_s + conv_b[o]; accumulate BN sum/sumsq.
//     Wave-per-point: lane = o; idx & P reads wave-uniform -> s_load.
//     2048 blocks x 4 waves x 4 points. NO register cap (round-2 spill lesson:
//     launch_bounds(256,8) forced VGPR 28 < the ~40 live floats -> scratch).
//     2-deep software pipeline: next point's idx s_load + 20 G-gathers issue
//     during current point's 400 FMAs (g[2][..] statically indexed, full unroll).
//     Last block finalizes BN stats (fused former k3).
// ---------------------------------------------------------------------------
__global__ __launch_bounds__(256) void k2_main(
        const int* __restrict__ nidx,
        const float* __restrict__ P,
        const float* __restrict__ G,
        const float* __restrict__ conv_b,
        float* __restrict__ omax,
        float* __restrict__ sums,
        unsigned* __restrict__ ctr,
        const float* __restrict__ bn_w,
        const float* __restrict__ bn_b,
        float* __restrict__ ss) {
    const int t = threadIdx.x;
    const int lane = t & 63;
    const int wid = t >> 6;
    const int base = __builtin_amdgcn_readfirstlane((blockIdx.x * 4 + wid) * 4);
    const float cb = conv_b[lane];
    float ls = 0.f, ls2 = 0.f;

    float g[2][KNB];                             // double-buffered gather rows

    // prologue: point 0 gathers
    {
        const int* ip = nidx + (size_t)base * KNB;
#pragma unroll
        for (int k = 0; k < KNB; ++k)
            g[0][k] = G[(size_t)ip[k] * 64 + lane];   // coalesced 256B row
    }

#pragma unroll
    for (int i = 0; i < 4; ++i) {
        const int cur = i & 1;                   // compile-time after unroll

        // issue next point's idx + gathers before consuming current
        if (i < 3) {
            const int* ip = nidx + (size_t)(base + i + 1) * KNB;
#pragma unroll
            for (int k = 0; k < KNB; ++k)
                g[cur ^ 1][k] = G[(size_t)ip[k] * 64 + lane];
        }

        float acc[KSZ];
#pragma unroll
        for (int s = 0; s < KSZ; ++s) acc[s] = 0.f;

        const float* pp = P + (size_t)(base + i) * (KNB * KSZ); // uniform -> s_load
#pragma unroll
        for (int k = 0; k < KNB; ++k) {
#pragma unroll
            for (int s = 0; s < KSZ; ++s)
                acc[s] += g[cur][k] * pp[k * KSZ + s];
        }

        float mx = acc[0];
#pragma unroll
        for (int s = 1; s < KSZ; ++s) mx = fmaxf(mx, acc[s]);
        mx += cb;
        omax[(size_t)(base + i) * 64 + lane] = mx;   // coalesced
        ls += mx;
        ls2 += mx * mx;
    }

    // block-level BN partial reduction, then 2 atomics per lane of wave 0
    __shared__ float r1[4][64], r2[4][64];
    r1[wid][lane] = ls;
    r2[wid][lane] = ls2;
    __syncthreads();
    if (wid == 0) {
        float a  = r1[0][lane] + r1[1][lane] + r1[2][lane] + r1[3][lane];
        float c2 = r2[0][lane] + r2[1][lane] + r2[2][lane] + r2[3][lane];
        atomicAdd(&sums[lane], a);
        atomicAdd(&sums[64 + lane], c2);
    }
    __syncthreads();

    // last-block stats finalize (former k3)
    __shared__ bool lastBlk;
    if (t == 0) {
        __threadfence();
        lastBlk = (atomicAdd(ctr, 1u) == (unsigned)(gridDim.x - 1));
    }
    __syncthreads();
    if (lastBlk && t < 64) {
        float s1 = atomicAdd(&sums[t], 0.f);         // coherent read
        float s2 = atomicAdd(&sums[64 + t], 0.f);
        const float inv = 1.f / (float)BN_TOT;
        float mean = s1 * inv;
        float var  = s2 * inv - mean * mean;
        float rstd = rsqrtf(var + BN_EPS);
        float sc = rstd * bn_w[t];
        ss[t] = sc;
        ss[64 + t] = bn_b[t] - mean * sc;
    }
}

// ---------------------------------------------------------------------------
// K4: apply BN + transpose [BN,64] -> [B,64,N]
//     512 blocks x 512 threads; wave w handles channels [w*8, w*8+8).
// ---------------------------------------------------------------------------
__global__ __launch_bounds__(512) void k4_apply(const float* __restrict__ omax,
                                                const float* __restrict__ ss,
                                                float* __restrict__ out) {
    const int b  = blockIdx.x >> 6;
    const int n0 = (blockIdx.x & 63) << 6;
    const int t  = threadIdx.x;
    const int nl = t & 63;
    const int ob = __builtin_amdgcn_readfirstlane((t >> 6) << 3);

    const size_t m = (size_t)b * N_PT + n0 + nl;
    const float4* src = reinterpret_cast<const float4*>(omax + m * 64 + ob);
    float v[8];
    float4 x0 = src[0], x1 = src[1];
    v[0] = x0.x; v[1] = x0.y; v[2] = x0.z; v[3] = x0.w;
    v[4] = x1.x; v[5] = x1.y; v[6] = x1.z; v[7] = x1.w;
#pragma unroll
    for (int j = 0; j < 8; ++j) {
        int o = ob + j;
        float sc = ss[o];                        // uniform -> s_load
        float sh = ss[64 + o];
        out[(size_t)b * C_OUT * N_PT + (size_t)o * N_PT + n0 + nl] =
            v[j] * sc + sh;                      // coalesced 256B store
    }
}

// ---------------------------------------------------------------------------
extern "C" void kernel_launch(void* const* d_in, const int* in_sizes, int n_in,
                              void* d_out, int out_size, void* d_ws, size_t ws_size,
                              hipStream_t stream) {
    const float* feature = (const float*)d_in[0];
    const int*   nidx    = (const int*)d_in[1];
    const float* perm    = (const float*)d_in[2];
    const float* conv_w  = (const float*)d_in[3];
    const float* conv_b  = (const float*)d_in[4];
    const float* bn_w    = (const float*)d_in[5];
    const float* bn_b    = (const float*)d_in[6];
    float* out = (float*)d_out;

    char* ws = (char*)d_ws;
    float* G    = (float*)ws;                                   // 8 MiB
    float* OM   = (float*)(ws + (size_t)8 * 1024 * 1024);       // 8 MiB
    float* W2T  = (float*)(ws + (size_t)16 * 1024 * 1024);      // 16 KiB
    float* SUMS = W2T + 4096;                                   // [0..127] sums
    unsigned* CTR = (unsigned*)(SUMS + 128);                    // [128] counter
    float* SS   = SUMS + 132;                                   // 128 floats

    k0_prep<<<16, 256, 0, stream>>>(conv_w, W2T, SUMS);
    k1_gemm<<<512, 512, 0, stream>>>(feature, W2T, G);
    k2_main<<<2048, 256, 0, stream>>>(nidx, perm, G, conv_b, OM, SUMS, CTR,
                                      bn_w, bn_b, SS);
    k4_apply<<<512, 512, 0, stream>>>(OM, SS, out);
}

// Round 6
// 206.140 us; speedup vs baseline: 1.1514x; 1.1514x over previous
//
#include <hip/hip_runtime.h>

#define C_IN 64
#define N_PT 4096
#define BN_TOT 32768          // B*N
#define KNB 20                // neighbors
#define KSZ 20                // kernel_size
#define C_OUT 64
#define BN_EPS 1e-5f
#define PPB 16                // points per k2 block

// ---------------------------------------------------------------------------
// K1: G[m][o] = sum_c conv_w[o][smap(c)] * feature[b][c][n],  m = b*N + n
//     smap fused into LDS staging (no separate w2t buffer / k0 kernel).
//     512 blocks x 512 threads. Wave w: o in [w*8,w*8+8), lane = point.
//     Weights read from LDS via broadcast ds_read_b128 (NOT s_load streams —
//     rounds 1-4 lesson: scalar-operand streaming serializes on SGPR budget).
//     Block 0 also zeroes the BN sums + last-block counter (ws is 0xAA-poisoned).
// ---------------------------------------------------------------------------
__global__ __launch_bounds__(512) void k1_gemm(const float* __restrict__ feat,
                                               const float* __restrict__ conv_w,
                                               float* __restrict__ G,
                                               float* __restrict__ sums) {
    __shared__ float fl[C_IN * 64];              // feature [c][p], 16 KiB
    __shared__ float wl[C_IN * C_OUT];           // shuffled weights [c][o], 16 KiB
    const int b  = blockIdx.x >> 6;
    const int n0 = (blockIdx.x & 63) << 6;
    const int t  = threadIdx.x;

    if (blockIdx.x == 0 && t < 132) sums[t] = 0.f;   // sums[128]=ctr, +spare

    // stage feature tile (coalesced float4)
    const float4* fsrc = reinterpret_cast<const float4*>(
        feat + (size_t)b * C_IN * N_PT + n0);
    float4* fl4 = reinterpret_cast<float4*>(fl);
#pragma unroll
    for (int j = 0; j < 2; ++j) {
        int idx = j * 512 + t;                   // 0..1023 float4 slots
        int c = idx >> 4, p4 = idx & 15;
        fl4[idx] = fsrc[c * (N_PT / 4) + p4];
    }
    // stage weights with channel shuffle: wl[smap^{-1}(co)][o] = conv_w[o][co]
#pragma unroll
    for (int j = 0; j < 8; ++j) {
        int i = j * 512 + t;                     // 0..4095, coalesced read
        int o = i >> 6, co = i & 63;
        int cn = ((co & 3) << 4) | (co >> 2);    // smap^{-1}
        wl[cn * 64 + o] = conv_w[i];             // one-time LDS scatter
    }
    __syncthreads();

    const int lane = t & 63;
    const int ob = (t >> 6) << 3;                // 0,8,...,56 (wave-uniform)

    float acc[8];
#pragma unroll
    for (int j = 0; j < 8; ++j) acc[j] = 0.f;

#pragma unroll 4
    for (int c = 0; c < C_IN; ++c) {
        float fc = fl[c * 64 + lane];            // stride-1, conflict-free
        float4 w0 = *reinterpret_cast<const float4*>(&wl[c * 64 + ob]);
        float4 w1 = *reinterpret_cast<const float4*>(&wl[c * 64 + ob + 4]);
        acc[0] += fc * w0.x; acc[1] += fc * w0.y;
        acc[2] += fc * w0.z; acc[3] += fc * w0.w;
        acc[4] += fc * w1.x; acc[5] += fc * w1.y;
        acc[6] += fc * w1.z; acc[7] += fc * w1.w;
    }

    size_t m = (size_t)b * N_PT + n0 + lane;
    float4* gdst = reinterpret_cast<float4*>(G + m * 64 + ob);
    gdst[0] = make_float4(acc[0], acc[1], acc[2], acc[3]);
    gdst[1] = make_float4(acc[4], acc[5], acc[6], acc[7]);
}

// ---------------------------------------------------------------------------
// K2: per point n: out[o,s] = sum_k G[idx[n,k]][o] * P[n][k][s]
//     omax[n][o] = max_s + conv_b[o]; accumulate BN sum/sumsq.
//     2048 blocks x 256 thr; block stages its 16 points' P (25.6 KB, contiguous
//     -> coalesced float4) + idx into LDS. FMA loop reads P via broadcast
//     ds_read_b128 (conflict-free, no SGPR-stream serialization).
//     Wave = 4 points, lane = o; G-gathers (coalesced 256B rows) double-buffered
//     so next point's gathers fly under current point's 400 FMAs.
//     Last block finalizes BN stats.
// ---------------------------------------------------------------------------
__global__ __launch_bounds__(256) void k2_main(
        const int* __restrict__ nidx,
        const float* __restrict__ P,
        const float* __restrict__ G,
        const float* __restrict__ conv_b,
        float* __restrict__ omax,
        float* __restrict__ sums,
        unsigned* __restrict__ ctr,
        const float* __restrict__ bn_w,
        const float* __restrict__ bn_b,
        float* __restrict__ ss) {
    __shared__ float Pl[PPB * KNB * KSZ];        // 6400 floats, 25.6 KiB
    __shared__ int   Il[PPB * KNB];              // 320 ints
    const int t = threadIdx.x;
    const int base = blockIdx.x * PPB;

    // stage P: 1600 float4 (contiguous), 256 thr
    const float4* ps = reinterpret_cast<const float4*>(P + (size_t)base * (KNB * KSZ));
    float4* pd = reinterpret_cast<float4*>(Pl);
#pragma unroll
    for (int j = 0; j < 6; ++j) pd[j * 256 + t] = ps[j * 256 + t];
    if (t < 64) pd[1536 + t] = ps[1536 + t];
    // stage idx: 80 int4
    if (t < 80)
        reinterpret_cast<int4*>(Il)[t] =
            reinterpret_cast<const int4*>(nidx + (size_t)base * KNB)[t];
    __syncthreads();

    const int lane = t & 63;
    const int wid = t >> 6;
    const int p0 = wid * 4;                      // first local point (uniform)
    const float cb = conv_b[lane];
    float ls = 0.f, ls2 = 0.f;

    float g[2][KNB];                             // double-buffered gather rows

    // prologue: local point p0 gathers (idx broadcast from LDS)
#pragma unroll
    for (int k = 0; k < KNB; ++k)
        g[0][k] = G[(size_t)Il[p0 * KNB + k] * 64 + lane];   // 256B row

#pragma unroll
    for (int i = 0; i < 4; ++i) {
        const int cur = i & 1;                   // compile-time after unroll

        if (i < 3) {                             // prefetch next point's rows
#pragma unroll
            for (int k = 0; k < KNB; ++k)
                g[cur ^ 1][k] = G[(size_t)Il[(p0 + i + 1) * KNB + k] * 64 + lane];
        }

        float acc[KSZ];
#pragma unroll
        for (int s = 0; s < KSZ; ++s) acc[s] = 0.f;

        const float* pp = Pl + (p0 + i) * (KNB * KSZ);
#pragma unroll
        for (int k = 0; k < KNB; ++k) {
#pragma unroll
            for (int s4 = 0; s4 < 5; ++s4) {     // 5x ds_read_b128 broadcast
                float4 pv = *reinterpret_cast<const float4*>(&pp[k * KSZ + s4 * 4]);
                acc[s4 * 4 + 0] += g[cur][k] * pv.x;
                acc[s4 * 4 + 1] += g[cur][k] * pv.y;
                acc[s4 * 4 + 2] += g[cur][k] * pv.z;
                acc[s4 * 4 + 3] += g[cur][k] * pv.w;
            }
        }

        float mx = acc[0];
#pragma unroll
        for (int s = 1; s < KSZ; ++s) mx = fmaxf(mx, acc[s]);
        mx += cb;
        omax[(size_t)(base + p0 + i) * 64 + lane] = mx;      // coalesced
        ls += mx;
        ls2 += mx * mx;
    }

    // BN partial reduction (reuse Pl after barrier), 2 atomics/lane of wave 0
    __syncthreads();                             // all Pl reads drained
    float* r1 = Pl;                              // [4][64]
    float* r2 = Pl + 256;                        // [4][64]
    r1[wid * 64 + lane] = ls;
    r2[wid * 64 + lane] = ls2;
    __syncthreads();
    if (wid == 0) {
        float a  = r1[lane] + r1[64 + lane] + r1[128 + lane] + r1[192 + lane];
        float c2 = r2[lane] + r2[64 + lane] + r2[128 + lane] + r2[192 + lane];
        atomicAdd(&sums[lane], a);
        atomicAdd(&sums[64 + lane], c2);
    }
    __syncthreads();

    // last-block stats finalize
    __shared__ bool lastBlk;
    if (t == 0) {
        __threadfence();
        lastBlk = (atomicAdd(ctr, 1u) == (unsigned)(gridDim.x - 1));
    }
    __syncthreads();
    if (lastBlk && t < 64) {
        float s1 = atomicAdd(&sums[t], 0.f);     // coherent read
        float s2 = atomicAdd(&sums[64 + t], 0.f);
        const float inv = 1.f / (float)BN_TOT;
        float mean = s1 * inv;
        float var  = s2 * inv - mean * mean;
        float rstd = rsqrtf(var + BN_EPS);
        float sc = rstd * bn_w[t];
        ss[t] = sc;
        ss[64 + t] = bn_b[t] - mean * sc;
    }
}

// ---------------------------------------------------------------------------
// K4: apply BN + transpose [BN,64] -> [B,64,N]
//     512 blocks x 512 threads; wave w handles channels [w*8, w*8+8).
// ---------------------------------------------------------------------------
__global__ __launch_bounds__(512) void k4_apply(const float* __restrict__ omax,
                                                const float* __restrict__ ss,
                                                float* __restrict__ out) {
    const int b  = blockIdx.x >> 6;
    const int n0 = (blockIdx.x & 63) << 6;
    const int t  = threadIdx.x;
    const int nl = t & 63;
    const int ob = (t >> 6) << 3;

    const size_t m = (size_t)b * N_PT + n0 + nl;
    const float4* src = reinterpret_cast<const float4*>(omax + m * 64 + ob);
    float v[8];
    float4 x0 = src[0], x1 = src[1];
    v[0] = x0.x; v[1] = x0.y; v[2] = x0.z; v[3] = x0.w;
    v[4] = x1.x; v[5] = x1.y; v[6] = x1.z; v[7] = x1.w;
#pragma unroll
    for (int j = 0; j < 8; ++j) {
        int o = ob + j;
        float sc = ss[o];                        // 16 uniform scalars: fine
        float sh = ss[64 + o];
        out[(size_t)b * C_OUT * N_PT + (size_t)o * N_PT + n0 + nl] =
            v[j] * sc + sh;                      // coalesced 256B store
    }
}

// ---------------------------------------------------------------------------
extern "C" void kernel_launch(void* const* d_in, const int* in_sizes, int n_in,
                              void* d_out, int out_size, void* d_ws, size_t ws_size,
                              hipStream_t stream) {
    const float* feature = (const float*)d_in[0];
    const int*   nidx    = (const int*)d_in[1];
    const float* perm    = (const float*)d_in[2];
    const float* conv_w  = (const float*)d_in[3];
    const float* conv_b  = (const float*)d_in[4];
    const float* bn_w    = (const float*)d_in[5];
    const float* bn_b    = (const float*)d_in[6];
    float* out = (float*)d_out;

    char* ws = (char*)d_ws;
    float* G    = (float*)ws;                                   // 8 MiB
    float* OM   = (float*)(ws + (size_t)8 * 1024 * 1024);       // 8 MiB
    float* SUMS = (float*)(ws + (size_t)16 * 1024 * 1024);      // [0..127] sums
    unsigned* CTR = (unsigned*)(SUMS + 128);                    // [128] counter
    float* SS   = SUMS + 132;                                   // 128 floats

    k1_gemm<<<512, 512, 0, stream>>>(feature, conv_w, G, SUMS);
    k2_main<<<BN_TOT / PPB, 256, 0, stream>>>(nidx, perm, G, conv_b, OM, SUMS,
                                              CTR, bn_w, bn_b, SS);
    k4_apply<<<512, 512, 0, stream>>>(OM, SS, out);
}